// Round 4
// baseline (930.683 us; speedup 1.0000x reference)
//
#include <hip/hip_runtime.h>

#define S_LEN 4096
#define DIM 64
#define NHEAD 64        // B*H = 4*16
#define NCHUNK 8
#define CHUNK (S_LEN / NCHUNK)   // 512 s-rows per block
#define WROWS (CHUNK / 4)        // 128 s-rows per wave
#define PHEAD 4160      // e-major KV^T: [e*64+d] for e,d<64 ; [4096+d] = Ksum[d]

__device__ __forceinline__ float elu1(float x) {
    // elu(x)+1 : x>0 -> x+1 ; x<=0 -> exp(x)
    return x > 0.0f ? x + 1.0f : __expf(x);
}

// bank-decorrelating bijection within a 64-element d-row:
// for the epilogue's fixed (i,j) scatter this makes lane banks 8(tx+i)+ty+j -> 2-way (free)
__device__ __forceinline__ int dswz(int d) { return ((d & 7) << 3) | (d >> 3); }

// ---------------- pass 1: partial KV^T (64x64) + Ksum per (head, chunk) ----------------
// 4 waves, each owns a private 128-row s-range; 8x8 register tile per lane with
// STATIC indexing only (dynamic indexing of acc[][] forces scratch spill — the
// round-2/3 disease: WRITE_SIZE 277MB vs 8.5MB useful). Waves combine via LDS
// atomicAdd on a bitswap-swizzled layout (2-way banks, free).
__global__ __launch_bounds__(256, 4) void pass1_kv(
    const float* __restrict__ K, const float* __restrict__ V,
    const float* __restrict__ mask, float* __restrict__ partials)
{
    const int head  = blockIdx.x >> 3;
    const int chunk = blockIdx.x & 7;
    const int t    = threadIdx.x;
    const int lane = t & 63;
    const int wave = t >> 6;      // 0..3
    const int tx = lane & 7;      // e-group: e = tx*8 + j
    const int ty = lane >> 3;     // d-group: d = ty*8 + i

    __shared__ float sm[65 * 65];   // sm[e*65 + dswz(d)], row 64 (off 4160) = ksum
    for (int i = t; i < 65 * 65; i += 256) sm[i] = 0.f;
    __syncthreads();   // zeros visible before any atomics

    float acc[8][8] = {};
    float ks[8] = {};

    const long hbase = (long)head * S_LEN * DIM;
    const int  s0    = chunk * CHUNK + wave * WROWS;
    const float* kp = K + hbase + (long)s0 * DIM + ty * 8;
    const float* vp = V + hbase + (long)s0 * DIM + tx * 8;
    const float* mp = mask + head * S_LEN + s0;

    #pragma unroll 2
    for (int s = 0; s < WROWS; ++s) {
        const float4 ka = *(const float4*)(kp + s * DIM);
        const float4 kb = *(const float4*)(kp + s * DIM + 4);
        const float4 va = *(const float4*)(vp + s * DIM);
        const float4 vb = *(const float4*)(vp + s * DIM + 4);
        const float m = mp[s];
        float kk[8], vv[8];
        kk[0] = elu1(ka.x) * m; kk[1] = elu1(ka.y) * m; kk[2] = elu1(ka.z) * m; kk[3] = elu1(ka.w) * m;
        kk[4] = elu1(kb.x) * m; kk[5] = elu1(kb.y) * m; kk[6] = elu1(kb.z) * m; kk[7] = elu1(kb.w) * m;
        vv[0] = va.x; vv[1] = va.y; vv[2] = va.z; vv[3] = va.w;
        vv[4] = vb.x; vv[5] = vb.y; vv[6] = vb.z; vv[7] = vb.w;
        #pragma unroll
        for (int i = 0; i < 8; ++i) {
            #pragma unroll
            for (int j = 0; j < 8; ++j) acc[i][j] += kk[i] * vv[j];
            ks[i] += kk[i];
        }
    }

    // combine 4 waves: constant-index scatter-add; dswz(ty*8+i) == i*8+ty
    #pragma unroll
    for (int i = 0; i < 8; ++i) {
        #pragma unroll
        for (int j = 0; j < 8; ++j)
            atomicAdd(&sm[(tx * 8 + j) * 65 + (i * 8 + ty)], acc[i][j]);
    }
    if (tx == 0) {    // ks duplicated across the 8 tx lanes; add once per wave
        #pragma unroll
        for (int i = 0; i < 8; ++i) atomicAdd(&sm[4160 + i * 8 + ty], ks[i]);
    }
    __syncthreads();

    // store partial (e-major): P[e*64+d], P[4096+d] = ksum
    float* P = partials + (long)(head * NCHUNK + chunk) * PHEAD;
    for (int idx = t; idx < PHEAD; idx += 256) {
        const int e = idx >> 6, d = idx & 63;
        P[idx] = (idx < 4096) ? sm[e * 65 + dswz(d)] : sm[4160 + dswz(d)];
    }
}

// ---------------- reduce: sum NCHUNK partials -> final KV^T (+Ksum) per head ----------------
__global__ __launch_bounds__(256) void reduce_kv(
    const float* __restrict__ partials, float* __restrict__ kvf)
{
    const int head = blockIdx.x;
    for (int idx = threadIdx.x; idx < PHEAD; idx += 256) {
        float s = 0.f;
        #pragma unroll
        for (int c = 0; c < NCHUNK; ++c)
            s += partials[(long)(head * NCHUNK + c) * PHEAD + idx];
        kvf[(long)head * PHEAD + idx] = s;
    }
}

// ---------------- pass 2: out = (Qf @ KV) * (1 / (Qf . Ksum)) ----------------
// Per-lane row: q[64] in VGPRs (direct global float4 loads), KV+Ksum staged once
// into 16.6KB LDS and read as broadcast ds_read_b128 (all lanes same address ->
// conflict-free). 4-way split accumulators break the FMA dependency chain.
__global__ __launch_bounds__(256, 4) void pass2_out(
    const float* __restrict__ Q, const float* __restrict__ kvf,
    float* __restrict__ out)
{
    const int head = blockIdx.x >> 4;
    const int tile = blockIdx.x & 15;
    const int t    = threadIdx.x;
    const int lane = t & 63;
    const int wave = t >> 6;
    const int row  = tile * 256 + wave * 64 + lane;

    __shared__ float kv[PHEAD];   // 16.6 KB: rows e (64 floats each), ksum at 4096

    const float* kvsrc = kvf + (long)head * PHEAD;
    for (int i = t; i < PHEAD / 4; i += 256)
        *(float4*)&kv[i * 4] = *(const float4*)(kvsrc + i * 4);
    __syncthreads();

    const long hbase = (long)head * S_LEN * DIM;
    const float* qp = Q + hbase + (long)row * DIM;

    float q[64];
    #pragma unroll
    for (int i = 0; i < 16; ++i) {
        const float4 v = *(const float4*)(qp + i * 4);
        q[i * 4 + 0] = elu1(v.x); q[i * 4 + 1] = elu1(v.y);
        q[i * 4 + 2] = elu1(v.z); q[i * 4 + 3] = elu1(v.w);
    }

    // denominator: Qf . Ksum
    float d0 = 0.f, d1 = 0.f, d2 = 0.f, d3 = 0.f;
    #pragma unroll
    for (int i = 0; i < 16; ++i) {
        const float4 kk = *(const float4*)&kv[4096 + i * 4];
        d0 += q[i * 4 + 0] * kk.x; d1 += q[i * 4 + 1] * kk.y;
        d2 += q[i * 4 + 2] * kk.z; d3 += q[i * 4 + 3] * kk.w;
    }
    const float rz = 1.0f / (d0 + d1 + d2 + d3);

    float* op = out + hbase + (long)row * DIM;
    for (int eg = 0; eg < 16; ++eg) {
        float r[4];
        #pragma unroll
        for (int j = 0; j < 4; ++j) {
            const float* kr = &kv[(eg * 4 + j) * 64];
            float a0 = 0.f, a1 = 0.f, a2 = 0.f, a3 = 0.f;
            #pragma unroll
            for (int i = 0; i < 16; ++i) {
                const float4 kk = *(const float4*)&kr[i * 4];
                a0 += q[i * 4 + 0] * kk.x; a1 += q[i * 4 + 1] * kk.y;
                a2 += q[i * 4 + 2] * kk.z; a3 += q[i * 4 + 3] * kk.w;
            }
            r[j] = (a0 + a1 + a2 + a3) * rz;
        }
        *(float4*)(op + eg * 4) = make_float4(r[0], r[1], r[2], r[3]);
    }
}

extern "C" void kernel_launch(void* const* d_in, const int* in_sizes, int n_in,
                              void* d_out, int out_size, void* d_ws, size_t ws_size,
                              hipStream_t stream) {
    const float* Q    = (const float*)d_in[0];
    const float* K    = (const float*)d_in[1];
    const float* V    = (const float*)d_in[2];
    const float* mask = (const float*)d_in[3];
    float* out = (float*)d_out;

    float* partials = (float*)d_ws;                           // 64*8*4160 floats ≈ 8.5 MB
    float* kvf = partials + (long)NHEAD * NCHUNK * PHEAD;     // 64*4160 floats ≈ 1.1 MB

    pass1_kv<<<NHEAD * NCHUNK, 256, 0, stream>>>(K, V, mask, partials);
    reduce_kv<<<NHEAD, 256, 0, stream>>>(partials, kvf);
    pass2_out<<<NHEAD * 16, 256, 0, stream>>>(Q, kvf, out);
}